// Round 2
// baseline (454.348 us; speedup 1.0000x reference)
//
#include <hip/hip_runtime.h>
#include <hip/hip_bf16.h>
#include <math.h>

#define THETA 0.7f

typedef short short8 __attribute__((ext_vector_type(8)));
typedef float floatx4 __attribute__((ext_vector_type(4)));

__device__ __forceinline__ unsigned short f2bu(float f) {
    return __builtin_bit_cast(unsigned short, __float2bfloat16(f));
}
__device__ __forceinline__ float b2f(unsigned short u) {
    unsigned v = ((unsigned)u) << 16;
    return __builtin_bit_cast(float, v);
}
__device__ __forceinline__ float wsum64(float v) {
    v += __shfl_xor(v, 32); v += __shfl_xor(v, 16); v += __shfl_xor(v, 8);
    v += __shfl_xor(v, 4);  v += __shfl_xor(v, 2);  v += __shfl_xor(v, 1);
    return v;
}

// Weight prep: fused bf16 weight matrix Bw[2 chunks][64 n][384 k].
// Row padded to 384 (768 B, 64B-aligned) so each (row, tap) 64B segment is
// exactly one cache line. k = tap*32+cl (theta*Wc), 288+cl ((1-theta)*We),
// k >= 320 zero.
__global__ void cdc_prep(const float* __restrict__ Wc,
                         const float* __restrict__ We,
                         unsigned short* __restrict__ Bw)
{
    int idx = blockIdx.x * 256 + threadIdx.x;
    if (idx >= 2 * 64 * 384) return;
    int k = idx % 384;
    int n = (idx / 384) & 63;
    int chunk = idx / 24576;
    int c0 = chunk << 5;
    float v = 0.f;
    if (k < 288) {
        int tap = k >> 5, cl = k & 31;
        v = THETA * Wc[n * 576 + (c0 + cl) * 9 + tap];
    } else if (k < 320) {
        int cl = k - 288;
        v = (1.0f - THETA) * We[n * 64 + c0 + cl];
    }
    Bw[idx] = f2bu(v);
}

// Per-(b,c)-plane stats for closed-form GAP: one streaming pass over x.
// stats[plane*10 + {0:T, 1:R0, 2:R255, 3:C0, 4:C255, 5:x00, 6:x0_255,
// 7:x255_0, 8:x255_255, 9: sum|x(r-1)-x(r+1)| }]
// Block = one 256x256 plane, 1024 threads: j = tid&255 (column),
// seg = tid>>8 (64-row strip). Coalesced 1KB/row-step reads.
__global__ __launch_bounds__(1024) void cdc_stats(
    const float* __restrict__ x, float* __restrict__ stats)
{
    __shared__ float rT[16], rD[16], rR0[4], rR255[4], rC0[4], rC255[4], rCorn[4];
    const int tid  = threadIdx.x;
    const int j    = tid & 255;
    const int seg  = tid >> 8;          // uniform per wave (waves 0-3:0 .. 12-15:3)
    const int w    = tid >> 6;
    const int lane = tid & 63;
    const float* p = x + (size_t)blockIdx.x * 65536 + j;

    const int r0 = seg << 6;
    float colsum = 0.f, D = 0.f;
    float xm = (r0 == 0) ? 0.f : p[(size_t)(r0 - 1) * 256];
    float xc = p[(size_t)r0 * 256];
    const float x_first = xc;           // row r0 value
    float x_last = 0.f;
    #pragma unroll 8
    for (int r = r0; r < r0 + 64; ++r) {
        float xp = (r + 1 < 256) ? p[(size_t)(r + 1) * 256] : 0.f;
        colsum += xc;
        D += fabsf(xm - xp);            // diff_v at output row r
        if (r == r0 + 63) x_last = xc;
        xm = xc; xc = xp;
    }

    float ts = wsum64(colsum);
    float ds = wsum64(D);
    if (lane == 0) { rT[w] = ts; rD[w] = ds; }
    if (seg == 0) {
        float fs = wsum64(x_first);
        if (lane == 0) rR0[w] = fs;
    } else if (seg == 3) {
        float fs = wsum64(x_last);
        if (lane == 0) rR255[w & 3] = fs;
    }
    if (j == 0) {
        rC0[seg] = colsum;
        if (seg == 0) rCorn[0] = x_first;        // x[0][0]
        if (seg == 3) rCorn[2] = x_last;         // x[255][0]
    }
    if (j == 255) {
        rC255[seg] = colsum;
        if (seg == 0) rCorn[1] = x_first;        // x[0][255]
        if (seg == 3) rCorn[3] = x_last;         // x[255][255]
    }
    __syncthreads();
    if (tid == 0) {
        float T = 0.f, Dt = 0.f;
        #pragma unroll
        for (int i = 0; i < 16; ++i) { T += rT[i]; Dt += rD[i]; }
        float* st = stats + (size_t)blockIdx.x * 10;
        st[0] = T;
        st[1] = rR0[0] + rR0[1] + rR0[2] + rR0[3];
        st[2] = rR255[0] + rR255[1] + rR255[2] + rR255[3];
        st[3] = rC0[0] + rC0[1] + rC0[2] + rC0[3];
        st[4] = rC255[0] + rC255[1] + rC255[2] + rC255[3];
        st[5] = rCorn[0]; st[6] = rCorn[1]; st[7] = rCorn[2]; st[8] = rCorn[3];
        st[9] = Dt;
    }
}

// Closed-form pooled -> SE MLP -> attn[b*64+o]. One block.
// S(ky,kx) = T - Rex[ky] - Cex[kx] + corner (inclusion-exclusion on the
// shifted window); pooled = theta*(conv_sum/65536 + bc) + (1-theta)*edge/65536.
__global__ __launch_bounds__(256) void cdc_attn(
    const float* __restrict__ stats, const float* __restrict__ Wc,
    const float* __restrict__ bc, const float* __restrict__ We,
    const float* __restrict__ W1, const float* __restrict__ b1,
    const float* __restrict__ W2, const float* __restrict__ b2,
    float* __restrict__ attn)
{
    __shared__ float S9[512][9];
    __shared__ float Dl[512];
    __shared__ float pooled[512];
    __shared__ float hb[64];
    const int tid = threadIdx.x;
    for (int i = tid; i < 512; i += 256) {
        const float* st = stats + (size_t)i * 10;
        float T = st[0], R0 = st[1], R255 = st[2], C0 = st[3], C255 = st[4];
        float Rex[3]  = {R255, 0.f, R0};          // indexed by ky
        float Cex[3]  = {C255, 0.f, C0};          // indexed by kx
        float corn[9] = {st[8], 0.f, st[7],       // (ky=0): x255_255, -, x255_0
                         0.f,   0.f, 0.f,
                         st[6], 0.f, st[5]};      // (ky=2): x0_255,  -, x00
        #pragma unroll
        for (int tap = 0; tap < 9; ++tap)
            S9[i][tap] = T - Rex[tap / 3] - Cex[tap % 3] + corn[tap];
        Dl[i] = st[9];
    }
    __syncthreads();
    for (int i = tid; i < 512; i += 256) {
        int b = i >> 6, o = i & 63;
        float cs = 0.f, es = 0.f;
        for (int c = 0; c < 64; ++c) {
            const float* wp = Wc + o * 576 + c * 9;
            const float* sp = S9[b * 64 + c];
            #pragma unroll
            for (int tap = 0; tap < 9; ++tap) cs += wp[tap] * sp[tap];
            es += We[o * 64 + c] * Dl[b * 64 + c];
        }
        pooled[i] = THETA * (cs * (1.f / 65536.f) + bc[o])
                  + (1.0f - THETA) * (es * (1.f / 65536.f));
    }
    __syncthreads();
    if (tid < 64) {
        int b = tid >> 3, r = tid & 7;
        float s = b1[r];
        for (int o = 0; o < 64; ++o) s += W1[r * 64 + o] * pooled[b * 64 + o];
        hb[tid] = fmaxf(s, 0.f);                  // hb[b*8+r]
    }
    __syncthreads();
    for (int i = tid; i < 512; i += 256) {
        int b = i >> 6, o = i & 63;
        float z = b2[o];
        #pragma unroll
        for (int r = 0; r < 8; ++r) z += W2[o * 8 + r] * hb[b * 8 + r];
        attn[i] = 1.0f / (1.0f + expf(-z));
    }
}

// Main: implicit-GEMM via 16x16x32 bf16 MFMA, attn applied at write time.
// Block = one 16x16 tile x 64 oc. LDS = xs only (31680 B); B-fragments read
// straight from L2-hot Bw (84 KB total, one 64B line per (row,tap)) -> with
// __launch_bounds__(256,4): 4 blocks/CU (was 2 with the 42 KB bs buffer).
// Bijective per-batch XCD swizzle (2048 % 8 == 0): XCD j owns batch j.
__global__ __launch_bounds__(256, 4) void cdc_main_kernel(
    const float* __restrict__ x, const unsigned short* __restrict__ Bw,
    const float* __restrict__ bc, const float* __restrict__ attn,
    float* __restrict__ out)
{
    __shared__ unsigned short xs[18 * 22 * 40];   // 31680 B

    const int tid  = threadIdx.x;
    const int lane = tid & 63;
    const int w    = tid >> 6;
    const int m    = lane & 15;   // A: pixel-in-frag (img col); B/D: oc-in-frag
    const int q    = lane >> 4;   // k-subchunk quad

    int wg = (int)blockIdx.x;
    wg = ((wg & 7) << 8) | (wg >> 3);   // XCD-contiguous, bijective
    const int b    = wg >> 8;
    const int t    = wg & 255;
    const int trow = ((t >> 4) & 15) << 4;
    const int tcol = (t & 15) << 4;

    const unsigned short* Bl = Bw + m * 384 + q * 8;   // per-lane weight base

    floatx4 acc[4][4];   // [mf][nf]; D: col=lane&15 (oc), row=q*4+reg (img col)
    #pragma unroll
    for (int nf = 0; nf < 4; ++nf) {
        float bias = THETA * bc[nf * 16 + m];
        #pragma unroll
        for (int mf = 0; mf < 4; ++mf)
            acc[mf][nf] = (floatx4){bias, bias, bias, bias};
    }

    for (int chunk = 0; chunk < 2; ++chunk) {
        const int c0 = chunk << 5;
        const unsigned short* Bc = Bl + chunk * 24576;
        __syncthreads();
        // ---- stage x chunk: 4x4 (col x c) transpose blocks, f32->bf16 ----
        for (int bi = tid; bi < 720; bi += 256) {
            const int cgrp = bi / 90;           // 0..7 (4 c each)
            const int rem  = bi - cgrp * 90;
            const int row  = rem / 5;           // 0..17 (halo rows)
            const int cg   = rem - row * 5;     // 0..4  (4 cols each)
            const int gr   = trow + row - 1;
            const int gc0  = tcol + (cg << 2) - 1;
            float v[4][4];
            const bool rok = (unsigned)gr < 256u;
            const float* xb = x + (((size_t)(b * 64 + c0 + cgrp * 4)) * 256 +
                                   (rok ? gr : 0)) * 256;
            if (rok && gc0 >= 0 && gc0 + 3 < 256) {
                #pragma unroll
                for (int i = 0; i < 4; ++i) {
                    float4 tv = *(const float4*)(xb + (size_t)i * 65536 + gc0);
                    v[i][0] = tv.x; v[i][1] = tv.y; v[i][2] = tv.z; v[i][3] = tv.w;
                }
            } else {
                #pragma unroll
                for (int i = 0; i < 4; ++i)
                    #pragma unroll
                    for (int e = 0; e < 4; ++e) {
                        int gc = gc0 + e;
                        v[i][e] = (rok && (unsigned)gc < 256u)
                                  ? xb[(size_t)i * 65536 + gc] : 0.f;
                    }
            }
            unsigned short* dst = &xs[(row * 22 + (cg << 2)) * 40 + (cgrp << 2)];
            #pragma unroll
            for (int e = 0; e < 4; ++e) {
                unsigned long long d =
                      (unsigned long long)f2bu(v[0][e])
                    | ((unsigned long long)f2bu(v[1][e]) << 16)
                    | ((unsigned long long)f2bu(v[2][e]) << 32)
                    | ((unsigned long long)f2bu(v[3][e]) << 48);
                *(unsigned long long*)(dst + e * 40) = d;
            }
        }
        __syncthreads();

        // ---- 9 conv ksteps; B-frags straight from global (L2-hot) ----
        #pragma unroll
        for (int tap = 0; tap < 9; ++tap) {
            const int dy = tap / 3, dx = tap % 3;
            short8 bf[4];
            #pragma unroll
            for (int nf = 0; nf < 4; ++nf)
                bf[nf] = *(const short8*)&Bc[nf * 6144 + tap * 32];
            #pragma unroll
            for (int mf = 0; mf < 4; ++mf) {
                const short8 af = *(const short8*)
                    &xs[((w * 4 + mf + dy) * 22 + (m + dx)) * 40 + q * 8];
                #pragma unroll
                for (int nf = 0; nf < 4; ++nf)
                    acc[mf][nf] = __builtin_amdgcn_mfma_f32_16x16x32_bf16(
                        af, bf[nf], acc[mf][nf], 0, 0, 0);
            }
        }
        // ---- edge kstep: A = |x(r-1) - x(r+1)| over 32 channels ----
        {
            short8 bf[4];
            #pragma unroll
            for (int nf = 0; nf < 4; ++nf)
                bf[nf] = *(const short8*)&Bc[nf * 6144 + 288];
            #pragma unroll
            for (int mf = 0; mf < 4; ++mf) {
                const short8 a0 = *(const short8*)
                    &xs[((w * 4 + mf) * 22 + m + 1) * 40 + q * 8];
                const short8 a1 = *(const short8*)
                    &xs[((w * 4 + mf + 2) * 22 + m + 1) * 40 + q * 8];
                short8 af;
                #pragma unroll
                for (int jj = 0; jj < 8; ++jj)
                    af[jj] = (short)f2bu(fabsf(
                        b2f((unsigned short)a0[jj]) - b2f((unsigned short)a1[jj])));
                #pragma unroll
                for (int nf = 0; nf < 4; ++nf)
                    acc[mf][nf] = __builtin_amdgcn_mfma_f32_16x16x32_bf16(
                        af, bf[nf], acc[mf][nf], 0, 0, 0);
            }
        }
    }

    // ---- apply attention and write final output ----
    float av[4];
    #pragma unroll
    for (int nf = 0; nf < 4; ++nf) av[nf] = attn[b * 64 + nf * 16 + m];
    #pragma unroll
    for (int mf = 0; mf < 4; ++mf) {
        const int y = trow + w * 4 + mf;
        #pragma unroll
        for (int nf = 0; nf < 4; ++nf) {
            const int oc = nf * 16 + m;
            size_t off = (((size_t)(b * 64 + oc)) * 256 + y) * 256 + tcol + q * 4;
            float4 val = make_float4(acc[mf][nf][0] * av[nf],
                                     acc[mf][nf][1] * av[nf],
                                     acc[mf][nf][2] * av[nf],
                                     acc[mf][nf][3] * av[nf]);
            *(float4*)(out + off) = val;
        }
    }
}

extern "C" void kernel_launch(void* const* d_in, const int* in_sizes, int n_in,
                              void* d_out, int out_size, void* d_ws, size_t ws_size,
                              hipStream_t stream)
{
    const float* x  = (const float*)d_in[0];
    const float* Wc = (const float*)d_in[1];
    const float* bc = (const float*)d_in[2];
    const float* We = (const float*)d_in[3];
    const float* W1 = (const float*)d_in[4];
    const float* b1 = (const float*)d_in[5];
    const float* W2 = (const float*)d_in[6];
    const float* b2 = (const float*)d_in[7];
    float* out  = (float*)d_out;

    float* stats = (float*)d_ws;                          // 5120 f32
    float* attn  = stats + 5120;                          // 512 f32
    unsigned short* Bw = (unsigned short*)(attn + 512);   // 2*64*384 bf16

    cdc_prep<<<192, 256, 0, stream>>>(Wc, We, Bw);
    cdc_stats<<<512, 1024, 0, stream>>>(x, stats);
    cdc_attn<<<1, 256, 0, stream>>>(stats, Wc, bc, We, W1, b1, W2, b2, attn);
    cdc_main_kernel<<<2048, 256, 0, stream>>>(x, Bw, bc, attn, out);
}